// Round 3
// baseline (487.755 us; speedup 1.0000x reference)
//
#include <hip/hip_runtime.h>

// RawISPProcessing: demosaic (bilinear 2x; flips are no-ops under the
// symmetric half-pixel grid) + folded (x2 * chflip * awb^T * ccm^T * chflip)
// 3x3 matrix + clip + gamma 1/2.2.
//
// R4b: one wave == one full 512-px source row (8 src px / lane, 2 float4 loads
// per row). Horizontal halos come from __shfl of the neighbor lane's edge
// values (zero VMEM) instead of 16B-stride scalar loads (which cost 16 L1
// lines each, same as a float4). Two output rows per thread (min 3x vertical
// read amp). 24 f4 loads + 24 f4 nontemporal stores per thread, no scalars.
// (R4 fix: nontemporal builtin needs ext_vector_type, not HIP float4 class.)

#define GAMMA_INV 0.45454545454545453f
#define EPS_CLIP 1e-8f

typedef float f32x4 __attribute__((ext_vector_type(4)));

__device__ __forceinline__ float gamma_enc(float v) {
  v = fmaxf(v, EPS_CLIP);
  return exp2f(GAMMA_INV * __log2f(v));
}

// One channel: 3 src rows x 8 cols, vertical blend -> e[8] (top), o[8] (bot);
// halos via in-wave shfl; horizontal 2x -> top[16], bot[16].
__device__ __forceinline__ void up2_row8(const float* __restrict__ ch,
                                         int jm, int j, int jp, int i, int lane,
                                         float top[16], float bot[16]) {
  const int W = 512;
  const float* r0 = ch + jm * W + i;
  const float* r1 = ch + j  * W + i;
  const float* r2 = ch + jp * W + i;
  f32x4 a0 = *reinterpret_cast<const f32x4*>(r0);
  f32x4 a1 = *reinterpret_cast<const f32x4*>(r0 + 4);
  f32x4 b0 = *reinterpret_cast<const f32x4*>(r1);
  f32x4 b1 = *reinterpret_cast<const f32x4*>(r1 + 4);
  f32x4 c0 = *reinterpret_cast<const f32x4*>(r2);
  f32x4 c1 = *reinterpret_cast<const f32x4*>(r2 + 4);
  float A[8]  = {a0.x, a0.y, a0.z, a0.w, a1.x, a1.y, a1.z, a1.w};
  float Bv[8] = {b0.x, b0.y, b0.z, b0.w, b1.x, b1.y, b1.z, b1.w};
  float Cv[8] = {c0.x, c0.y, c0.z, c0.w, c1.x, c1.y, c1.z, c1.w};
  float e[8], o[8];
#pragma unroll
  for (int c = 0; c < 8; ++c) {
    e[c] = 0.25f * A[c]  + 0.75f * Bv[c];   // even output row
    o[c] = 0.75f * Bv[c] + 0.25f * Cv[c];   // odd output row
  }
  // Halos: col 8*lane-1 == left lane's e[7]/o[7]; col 8*lane+8 == right
  // lane's e[0]/o[0]. Clamp at image edges (lane 0 / lane 63).
  float eL = __shfl_up(e[7], 1);   eL = (lane == 0)  ? e[0] : eL;
  float oL = __shfl_up(o[7], 1);   oL = (lane == 0)  ? o[0] : oL;
  float eR = __shfl_down(e[0], 1); eR = (lane == 63) ? e[7] : eR;
  float oR = __shfl_down(o[0], 1); oR = (lane == 63) ? o[7] : oR;
  top[0] = 0.25f * eL + 0.75f * e[0];
  bot[0] = 0.25f * oL + 0.75f * o[0];
#pragma unroll
  for (int p = 0; p < 7; ++p) {
    top[2 * p + 1] = 0.75f * e[p] + 0.25f * e[p + 1];
    top[2 * p + 2] = 0.25f * e[p] + 0.75f * e[p + 1];
    bot[2 * p + 1] = 0.75f * o[p] + 0.25f * o[p + 1];
    bot[2 * p + 2] = 0.25f * o[p] + 0.75f * o[p + 1];
  }
  top[15] = 0.75f * e[7] + 0.25f * eR;
  bot[15] = 0.75f * o[7] + 0.25f * oR;
}

__global__ __launch_bounds__(256) void isp_kernel(
    const float* __restrict__ pred, const float* __restrict__ gt,
    const float* __restrict__ awb, const float* __restrict__ ccm,
    float* __restrict__ out) {
  constexpr int H = 512, W = 512;
  constexpr int HW = H * W;
  constexpr long long OUT_IMG = 8LL * 3 * 1024 * 1024;

  int idx  = blockIdx.x * blockDim.x + threadIdx.x;  // 2*8*512*64 threads
  int tg   = idx & 63;           // col group: src cols [8tg, 8tg+7]
  int j    = (idx >> 6) & 511;   // src row
  int b    = (idx >> 15) & 7;    // batch
  int img  = idx >> 18;          // 0=pred, 1=gt
  int lane = tg;                 // wave == one full row; lane == tg

  // Folded color matrix: out[k] = 2 * sum_e v[e] * sum_c awb[2-e][c]*ccm[c][2-k]
  const float* A  = awb + b * 9;
  const float* Cm = ccm + b * 9;
  float M[3][3];
#pragma unroll
  for (int k = 0; k < 3; ++k) {
#pragma unroll
    for (int e = 0; e < 3; ++e) {
      int ar = (2 - e) * 3;
      int cc = 2 - k;
      M[k][e] = 2.0f * (A[ar + 0] * Cm[0 + cc] +
                        A[ar + 1] * Cm[3 + cc] +
                        A[ar + 2] * Cm[6 + cc]);
    }
  }

  int i  = 8 * tg;
  int jm = (j > 0) ? j - 1 : 0;
  int jp = (j < H - 1) ? j + 1 : H - 1;

  const float* src = (img ? gt : pred) + (long long)b * 4 * HW;

  float rT[16], rB[16], gT[16], gB[16], qT[16], qB[16];
  up2_row8(src + 0 * HW, jm, j, jp, i, lane, rT, rB);   // red
  up2_row8(src + 1 * HW, jm, j, jp, i, lane, gT, gB);   // Gr
  up2_row8(src + 2 * HW, jm, j, jp, i, lane, qT, qB);   // Gb
  // Green quad-parity combine: (ee)=avg, (eo)=Gr, (oe)=Gb, (oo)=avg.
#pragma unroll
  for (int p = 0; p < 8; ++p) {
    gT[2 * p]     = 0.5f * (gT[2 * p] + qT[2 * p]);
    /* gT[2p+1] stays Gr */
    gB[2 * p]     = qB[2 * p];
    gB[2 * p + 1] = 0.5f * (gB[2 * p + 1] + qB[2 * p + 1]);
  }
  up2_row8(src + 3 * HW, jm, j, jp, i, lane, qT, qB);   // blue (reuse q)

  int oy = 2 * j, ox = 16 * tg;
  float* dst = out + (long long)img * OUT_IMG;

#pragma unroll
  for (int k = 0; k < 3; ++k) {
    float oT[16], oB[16];
#pragma unroll
    for (int p = 0; p < 16; ++p) {
      oT[p] = gamma_enc(M[k][0] * rT[p] + M[k][1] * gT[p] + M[k][2] * qT[p]);
      oB[p] = gamma_enc(M[k][0] * rB[p] + M[k][1] * gB[p] + M[k][2] * qB[p]);
    }
    long long obase = ((long long)(b * 3 + k) * 1024 + oy) * 1024 + ox;
#pragma unroll
    for (int q = 0; q < 4; ++q) {
      f32x4 vT = {oT[4 * q], oT[4 * q + 1], oT[4 * q + 2], oT[4 * q + 3]};
      f32x4 vB = {oB[4 * q], oB[4 * q + 1], oB[4 * q + 2], oB[4 * q + 3]};
      __builtin_nontemporal_store(vT, reinterpret_cast<f32x4*>(dst + obase + 4 * q));
      __builtin_nontemporal_store(vB, reinterpret_cast<f32x4*>(dst + obase + 1024 + 4 * q));
    }
  }
}

extern "C" void kernel_launch(void* const* d_in, const int* in_sizes, int n_in,
                              void* d_out, int out_size, void* d_ws, size_t ws_size,
                              hipStream_t stream) {
  const float* pred = (const float*)d_in[0];
  const float* gt   = (const float*)d_in[1];
  const float* awb  = (const float*)d_in[2];
  const float* ccm  = (const float*)d_in[3];
  // d_in[4] = rgb_gain: unused by the reference.
  float* out = (float*)d_out;

  const int total = 2 * 8 * 512 * 64;  // img * batch * src-rows * col-groups
  dim3 block(256);
  dim3 grid(total / 256);
  isp_kernel<<<grid, block, 0, stream>>>(pred, gt, awb, ccm, out);
}

// Round 5
// 279.393 us; speedup vs baseline: 1.7458x; 1.7458x over previous
//
#include <hip/hip_runtime.h>

// RawISPProcessing: demosaic (bilinear 2x; flips are no-ops under the
// symmetric half-pixel grid) + folded (x2 * chflip * awb^T * ccm^T * chflip)
// 3x3 matrix + clip + gamma 1/2.2.
//
// R5: R4b structure (wave == one full 512-px source row, 8 px/lane, halos via
// __shfl, zero scalar loads) but with PLAIN float4 stores. R4b's nontemporal
// stores bypassed L2 write-combining -> 2.75x write amplification (WRITE_SIZE
// 553 MB vs 201 MB ideal) and 300us kernel. Plain stores let L2 combine the
// 4KB-contiguous per-wave bursts.

#define GAMMA_INV 0.45454545454545453f
#define EPS_CLIP 1e-8f

typedef float f32x4 __attribute__((ext_vector_type(4)));

__device__ __forceinline__ float gamma_enc(float v) {
  v = fmaxf(v, EPS_CLIP);
  return exp2f(GAMMA_INV * __log2f(v));
}

// One channel: 3 src rows x 8 cols, vertical blend -> e[8] (top), o[8] (bot);
// halos via in-wave shfl; horizontal 2x -> top[16], bot[16].
__device__ __forceinline__ void up2_row8(const float* __restrict__ ch,
                                         int jm, int j, int jp, int i, int lane,
                                         float top[16], float bot[16]) {
  const int W = 512;
  const float* r0 = ch + jm * W + i;
  const float* r1 = ch + j  * W + i;
  const float* r2 = ch + jp * W + i;
  f32x4 a0 = *reinterpret_cast<const f32x4*>(r0);
  f32x4 a1 = *reinterpret_cast<const f32x4*>(r0 + 4);
  f32x4 b0 = *reinterpret_cast<const f32x4*>(r1);
  f32x4 b1 = *reinterpret_cast<const f32x4*>(r1 + 4);
  f32x4 c0 = *reinterpret_cast<const f32x4*>(r2);
  f32x4 c1 = *reinterpret_cast<const f32x4*>(r2 + 4);
  float A[8]  = {a0.x, a0.y, a0.z, a0.w, a1.x, a1.y, a1.z, a1.w};
  float Bv[8] = {b0.x, b0.y, b0.z, b0.w, b1.x, b1.y, b1.z, b1.w};
  float Cv[8] = {c0.x, c0.y, c0.z, c0.w, c1.x, c1.y, c1.z, c1.w};
  float e[8], o[8];
#pragma unroll
  for (int c = 0; c < 8; ++c) {
    e[c] = 0.25f * A[c]  + 0.75f * Bv[c];   // even output row
    o[c] = 0.75f * Bv[c] + 0.25f * Cv[c];   // odd output row
  }
  // Halos: col 8*lane-1 == left lane's e[7]/o[7]; col 8*lane+8 == right
  // lane's e[0]/o[0]. Clamp at image edges (lane 0 / lane 63).
  float eL = __shfl_up(e[7], 1);   eL = (lane == 0)  ? e[0] : eL;
  float oL = __shfl_up(o[7], 1);   oL = (lane == 0)  ? o[0] : oL;
  float eR = __shfl_down(e[0], 1); eR = (lane == 63) ? e[7] : eR;
  float oR = __shfl_down(o[0], 1); oR = (lane == 63) ? o[7] : oR;
  top[0] = 0.25f * eL + 0.75f * e[0];
  bot[0] = 0.25f * oL + 0.75f * o[0];
#pragma unroll
  for (int p = 0; p < 7; ++p) {
    top[2 * p + 1] = 0.75f * e[p] + 0.25f * e[p + 1];
    top[2 * p + 2] = 0.25f * e[p] + 0.75f * e[p + 1];
    bot[2 * p + 1] = 0.75f * o[p] + 0.25f * o[p + 1];
    bot[2 * p + 2] = 0.25f * o[p] + 0.75f * o[p + 1];
  }
  top[15] = 0.75f * e[7] + 0.25f * eR;
  bot[15] = 0.75f * o[7] + 0.25f * oR;
}

__global__ __launch_bounds__(256) void isp_kernel(
    const float* __restrict__ pred, const float* __restrict__ gt,
    const float* __restrict__ awb, const float* __restrict__ ccm,
    float* __restrict__ out) {
  constexpr int H = 512, W = 512;
  constexpr int HW = H * W;
  constexpr long long OUT_IMG = 8LL * 3 * 1024 * 1024;

  int idx  = blockIdx.x * blockDim.x + threadIdx.x;  // 2*8*512*64 threads
  int tg   = idx & 63;           // col group: src cols [8tg, 8tg+7]
  int j    = (idx >> 6) & 511;   // src row
  int b    = (idx >> 15) & 7;    // batch
  int img  = idx >> 18;          // 0=pred, 1=gt
  int lane = tg;                 // wave == one full row; lane == tg

  // Folded color matrix: out[k] = 2 * sum_e v[e] * sum_c awb[2-e][c]*ccm[c][2-k]
  const float* A  = awb + b * 9;
  const float* Cm = ccm + b * 9;
  float M[3][3];
#pragma unroll
  for (int k = 0; k < 3; ++k) {
#pragma unroll
    for (int e = 0; e < 3; ++e) {
      int ar = (2 - e) * 3;
      int cc = 2 - k;
      M[k][e] = 2.0f * (A[ar + 0] * Cm[0 + cc] +
                        A[ar + 1] * Cm[3 + cc] +
                        A[ar + 2] * Cm[6 + cc]);
    }
  }

  int i  = 8 * tg;
  int jm = (j > 0) ? j - 1 : 0;
  int jp = (j < H - 1) ? j + 1 : H - 1;

  const float* src = (img ? gt : pred) + (long long)b * 4 * HW;

  float rT[16], rB[16], gT[16], gB[16], qT[16], qB[16];
  up2_row8(src + 0 * HW, jm, j, jp, i, lane, rT, rB);   // red
  up2_row8(src + 1 * HW, jm, j, jp, i, lane, gT, gB);   // Gr
  up2_row8(src + 2 * HW, jm, j, jp, i, lane, qT, qB);   // Gb
  // Green quad-parity combine: (ee)=avg, (eo)=Gr, (oe)=Gb, (oo)=avg.
#pragma unroll
  for (int p = 0; p < 8; ++p) {
    gT[2 * p]     = 0.5f * (gT[2 * p] + qT[2 * p]);
    /* gT[2p+1] stays Gr */
    gB[2 * p]     = qB[2 * p];
    gB[2 * p + 1] = 0.5f * (gB[2 * p + 1] + qB[2 * p + 1]);
  }
  up2_row8(src + 3 * HW, jm, j, jp, i, lane, qT, qB);   // blue (reuse q)

  int oy = 2 * j, ox = 16 * tg;
  float* dst = out + (long long)img * OUT_IMG;

#pragma unroll
  for (int k = 0; k < 3; ++k) {
    float oT[16], oB[16];
#pragma unroll
    for (int p = 0; p < 16; ++p) {
      oT[p] = gamma_enc(M[k][0] * rT[p] + M[k][1] * gT[p] + M[k][2] * qT[p]);
      oB[p] = gamma_enc(M[k][0] * rB[p] + M[k][1] * gB[p] + M[k][2] * qB[p]);
    }
    long long obase = ((long long)(b * 3 + k) * 1024 + oy) * 1024 + ox;
#pragma unroll
    for (int q = 0; q < 4; ++q) {
      f32x4 vT = {oT[4 * q], oT[4 * q + 1], oT[4 * q + 2], oT[4 * q + 3]};
      f32x4 vB = {oB[4 * q], oB[4 * q + 1], oB[4 * q + 2], oB[4 * q + 3]};
      *reinterpret_cast<f32x4*>(dst + obase + 4 * q)        = vT;
      *reinterpret_cast<f32x4*>(dst + obase + 1024 + 4 * q) = vB;
    }
  }
}

extern "C" void kernel_launch(void* const* d_in, const int* in_sizes, int n_in,
                              void* d_out, int out_size, void* d_ws, size_t ws_size,
                              hipStream_t stream) {
  const float* pred = (const float*)d_in[0];
  const float* gt   = (const float*)d_in[1];
  const float* awb  = (const float*)d_in[2];
  const float* ccm  = (const float*)d_in[3];
  // d_in[4] = rgb_gain: unused by the reference.
  float* out = (float*)d_out;

  const int total = 2 * 8 * 512 * 64;  // img * batch * src-rows * col-groups
  dim3 block(256);
  dim3 grid(total / 256);
  isp_kernel<<<grid, block, 0, stream>>>(pred, gt, awb, ccm, out);
}